// Round 1
// baseline (61.971 us; speedup 1.0000x reference)
//
#include <hip/hip_runtime.h>

#define HW 224
#define CHW (HW*HW)

__global__ __launch_bounds__(256) void patch_conv_kernel(
    const float* __restrict__ X,
    const float* __restrict__ Wt,   // [3][3][3][3] OIHW
    const float* __restrict__ Bv,   // [3]
    const float* __restrict__ P,    // [3136][48]
    float* __restrict__ out)        // [B][196][768]
{
    const int nc  = blockIdx.x;     // 0..195 coarse patch
    const int b   = blockIdx.y;     // 0..127 batch
    const int H0  = (nc / 14) * 16;
    const int W0  = (nc % 14) * 16;
    const int tid = threadIdx.x;

    __shared__ float lds[3][18][19];   // +1 pad on inner dim

    const float* Xb = X + (size_t)b * (3 * CHW);

    // Stage 18x18x3 halo tile (SAME padding -> zeros out of bounds)
    for (int idx = tid; idx < 3 * 18 * 18; idx += 256) {
        int ci  = idx / 324;
        int rem = idx - ci * 324;
        int y   = rem / 18;
        int x   = rem - y * 18;
        int h   = H0 - 1 + y;
        int w   = W0 - 1 + x;
        float v = 0.f;
        if ((unsigned)h < HW && (unsigned)w < HW)
            v = Xb[ci * CHW + h * HW + w];
        lds[ci][y][x] = v;
    }
    __syncthreads();

    const int ph = tid >> 4;
    const int pw = tid & 15;
    const int h  = H0 + ph;
    const int w  = W0 + pw;

    // position-embedding index at fine (p=4) granularity
    const int nf  = (h >> 2) * 56 + (w >> 2);
    const int sub = (h & 3) * 4 + (w & 3);
    const float* Pp = P + nf * 48 + sub;

    float acc0 = Bv[0] + Pp[0];
    float acc1 = Bv[1] + Pp[16];
    float acc2 = Bv[2] + Pp[32];

    #pragma unroll
    for (int ci = 0; ci < 3; ++ci) {
        #pragma unroll
        for (int ky = 0; ky < 3; ++ky) {
            float a0 = lds[ci][ph + ky][pw + 0];
            float a1 = lds[ci][ph + ky][pw + 1];
            float a2 = lds[ci][ph + ky][pw + 2];
            const float* w0 = Wt + ((0 * 3 + ci) * 3 + ky) * 3;
            const float* w1 = Wt + ((1 * 3 + ci) * 3 + ky) * 3;
            const float* w2 = Wt + ((2 * 3 + ci) * 3 + ky) * 3;
            acc0 += a0 * w0[0] + a1 * w0[1] + a2 * w0[2];
            acc1 += a0 * w1[0] + a1 * w1[1] + a2 * w1[2];
            acc2 += a0 * w2[0] + a1 * w2[1] + a2 * w2[2];
        }
    }

    // out[b, nc, co*256 + ph*16 + pw]; ph*16+pw == tid -> fully coalesced
    float* ob = out + (size_t)b * (196 * 768) + (size_t)nc * 768 + tid;
    ob[0]   = acc0;
    ob[256] = acc1;
    ob[512] = acc2;
}

extern "C" void kernel_launch(void* const* d_in, const int* in_sizes, int n_in,
                              void* d_out, int out_size, void* d_ws, size_t ws_size,
                              hipStream_t stream) {
    const float* X  = (const float*)d_in[0];
    const float* Wt = (const float*)d_in[1];
    const float* Bv = (const float*)d_in[2];
    const float* P  = (const float*)d_in[3];
    float* out = (float*)d_out;

    dim3 grid(196, 128);
    patch_conv_kernel<<<grid, 256, 0, stream>>>(X, Wt, Bv, P, out);
}

// Round 2
// 47.540 us; speedup vs baseline: 1.3036x; 1.3036x over previous
//
#include <hip/hip_runtime.h>

#define HW 224
#define CHW (HW*HW)
#define ROWS_PER_WAVE 7

__global__ __launch_bounds__(256) void patch_conv_kernel(
    const float* __restrict__ X,    // [B][3][224][224]
    const float* __restrict__ Wt,   // [3][3][3][3] OIHW
    const float* __restrict__ Bv,   // [3]
    const float* __restrict__ P,    // [3136][48]
    float* __restrict__ out)        // [B][196][768]
{
    const int b    = blockIdx.y;
    const int tid  = threadIdx.x;
    const int lane = tid & 63;
    const int wv   = tid >> 6;
    const int strip = blockIdx.x * 4 + wv;      // 0..31
    const int r0   = strip * ROWS_PER_WAVE;     // first output row of this wave
    const int x0   = lane * 4;                  // 0..252
    const bool act = (x0 < HW);                 // lanes 56..63 are padding lanes

    // Weights: uniform loads, compile-time offsets -> scalar loads / SGPRs
    float w[3][3][3][3];
    #pragma unroll
    for (int i = 0; i < 81; ++i)
        ((float*)w)[i] = Wt[i];
    const float b0 = Bv[0], b1 = Bv[1], b2 = Bv[2];

    const float* Xb = X + (size_t)b * (3 * CHW);

    // rolling window: e[ci][slot][6] = {left, v0, v1, v2, v3, right}
    // e[k] == X[x0 + k - 1]
    float e[3][3][6];

    auto load_row = [&](int ci, int y, float* dst) {
        float4 v = make_float4(0.f, 0.f, 0.f, 0.f);
        if ((unsigned)y < HW && act)
            v = *(const float4*)(Xb + ci * CHW + y * HW + x0);
        float l  = __shfl_up(v.w, 1);
        float rr = __shfl_down(v.x, 1);
        if (lane == 0) l = 0.f;          // x == -1 pad
        if (x0 + 4 >= HW) rr = 0.f;      // x == 224 pad
        dst[0] = l; dst[1] = v.x; dst[2] = v.y; dst[3] = v.z; dst[4] = v.w; dst[5] = rr;
    };

    // prime: rows r0-1, r0, r0+1 into slots 0,1,2
    #pragma unroll
    for (int ci = 0; ci < 3; ++ci) {
        load_row(ci, r0 - 1, e[ci][0]);
        load_row(ci, r0,     e[ci][1]);
        load_row(ci, r0 + 1, e[ci][2]);
    }

    const int nc_col = x0 >> 4;   // patch column (0..13)
    const int xl     = x0 & 15;   // offset inside 16-wide patch (0,4,8,12)
    const int nf_col = x0 >> 2;   // fine-patch column (0..55)

    float* ob = out + (size_t)b * (196 * 768);

    #pragma unroll
    for (int i = 0; i < ROWS_PER_WAVE; ++i) {
        const int y   = r0 + i;
        const int sm1 = i % 3, s0 = (i + 1) % 3, sp1 = (i + 2) % 3;

        float acc[3][4];
        #pragma unroll
        for (int co = 0; co < 3; ++co)
            #pragma unroll
            for (int j = 0; j < 4; ++j) acc[co][j] = 0.f;

        #pragma unroll
        for (int ci = 0; ci < 3; ++ci) {
            const float* rows[3] = { e[ci][sm1], e[ci][s0], e[ci][sp1] };
            #pragma unroll
            for (int kh = 0; kh < 3; ++kh) {
                const float* rr = rows[kh];
                #pragma unroll
                for (int co = 0; co < 3; ++co) {
                    const float w0 = w[co][ci][kh][0];
                    const float w1 = w[co][ci][kh][1];
                    const float w2 = w[co][ci][kh][2];
                    #pragma unroll
                    for (int j = 0; j < 4; ++j)
                        acc[co][j] += w0 * rr[j] + w1 * rr[j + 1] + w2 * rr[j + 2];
                }
            }
        }

        // refill the slot holding row y-1 with row y+2 (used two iters later)
        #pragma unroll
        for (int ci = 0; ci < 3; ++ci)
            load_row(ci, y + 2, e[ci][sm1]);

        if (act) {
            const int nf  = (y >> 2) * 56 + nf_col;         // fine patch index
            const int sub = (y & 3) * 4;                    // sub-offset base
            const int nc  = (y >> 4) * 14 + nc_col;         // coarse patch index
            float* op = ob + nc * 768 + (y & 15) * 16 + xl;

            const float4 p0 = *(const float4*)(P + nf * 48 + 0 * 16 + sub);
            const float4 p1 = *(const float4*)(P + nf * 48 + 1 * 16 + sub);
            const float4 p2 = *(const float4*)(P + nf * 48 + 2 * 16 + sub);

            *(float4*)(op + 0)   = make_float4(acc[0][0] + b0 + p0.x, acc[0][1] + b0 + p0.y,
                                               acc[0][2] + b0 + p0.z, acc[0][3] + b0 + p0.w);
            *(float4*)(op + 256) = make_float4(acc[1][0] + b1 + p1.x, acc[1][1] + b1 + p1.y,
                                               acc[1][2] + b1 + p1.z, acc[1][3] + b1 + p1.w);
            *(float4*)(op + 512) = make_float4(acc[2][0] + b2 + p2.x, acc[2][1] + b2 + p2.y,
                                               acc[2][2] + b2 + p2.z, acc[2][3] + b2 + p2.w);
        }
    }
}

extern "C" void kernel_launch(void* const* d_in, const int* in_sizes, int n_in,
                              void* d_out, int out_size, void* d_ws, size_t ws_size,
                              hipStream_t stream) {
    const float* X  = (const float*)d_in[0];
    const float* Wt = (const float*)d_in[1];
    const float* Bv = (const float*)d_in[2];
    const float* P  = (const float*)d_in[3];
    float* out = (float*)d_out;

    // 32 strips of 7 rows per image; 4 waves (strips) per block of 256
    dim3 grid(8, 128);
    patch_conv_kernel<<<grid, 256, 0, stream>>>(X, Wt, Bv, P, out);
}